// Round 3
// baseline (1315.629 us; speedup 1.0000x reference)
//
#include <hip/hip_runtime.h>

// ---------------------------------------------------------------------------
// LiteTracker correlation-pyramid hot path. FP32 in/out, bf16 internal staging.
// Level x 1024-point chunks (ws = 12.0 MB):
//   k_prep: fmaps [C,HW] -> fmapT [HW,128] bf16 ; w1 -> W1T [384,2432] bf16
//           (zero-padded K) ; w2 -> W2T [256,384] bf16
//   per (level, chunk): k_corr  -> X [1024,2432] bf16
//                       k_gemm1 -> GELU -> H [1024,384] bf16
//                       k_gemm2 -> out[n0.., lvl*256..] fp32
// Input-order detection via in_sizes (dict / ref-arg / alphabetical).
// ---------------------------------------------------------------------------

typedef __bf16 bf16x8 __attribute__((ext_vector_type(8)));
typedef float f32x4 __attribute__((ext_vector_type(4)));

#define KPAD 2432          // 2401 padded to 76*32
#define K_RAW 2401
#define NPTS 4096
#define CHUNK 1024

__device__ __forceinline__ float b2f(unsigned short u) {
    return __uint_as_float(((unsigned int)u) << 16);
}
__device__ __forceinline__ unsigned short f2b(float f) {
    unsigned int u = __float_as_uint(f);
    u += 0x7fffu + ((u >> 16) & 1u);   // round-to-nearest-even
    return (unsigned short)(u >> 16);
}
__device__ __forceinline__ void unpack8(uint4 v, float* f) {
    f[0] = b2f((unsigned short)(v.x & 0xffffu)); f[1] = b2f((unsigned short)(v.x >> 16));
    f[2] = b2f((unsigned short)(v.y & 0xffffu)); f[3] = b2f((unsigned short)(v.y >> 16));
    f[4] = b2f((unsigned short)(v.z & 0xffffu)); f[5] = b2f((unsigned short)(v.z >> 16));
    f[6] = b2f((unsigned short)(v.w & 0xffffu)); f[7] = b2f((unsigned short)(v.w >> 16));
}
__device__ __forceinline__ uint4 pack8(const float* f) {
    unsigned short pk[8];
#pragma unroll
    for (int j = 0; j < 8; ++j) pk[j] = f2b(f[j]);
    uint4 o;
    o.x = pk[0] | ((unsigned int)pk[1] << 16);
    o.y = pk[2] | ((unsigned int)pk[3] << 16);
    o.z = pk[4] | ((unsigned int)pk[5] << 16);
    o.w = pk[6] | ((unsigned int)pk[7] << 16);
    return o;
}

// ---------------------------------------------------------------------------
// k_prep. Region A: fmap transpose, source-linear (coalesced reads, scattered
// bf16 writes absorbed by L2). Regions B/C: weight transposes, dest-linear.
// total elems: 2,088,960 + 933,888 + 98,304 = 3,121,152 -> grid 12192 x 256
// ---------------------------------------------------------------------------
__global__ __launch_bounds__(256) void k_prep(
    const float* __restrict__ f0, const float* __restrict__ f1,
    const float* __restrict__ f2, const float* __restrict__ f3,
    const float* __restrict__ w1, const float* __restrict__ w2,
    unsigned short* __restrict__ fmapT, unsigned short* __restrict__ W1T,
    unsigned short* __restrict__ W2T)
{
    int idx = blockIdx.x * 256 + threadIdx.x;
    const int FT = 2088960;
    if (idx < FT) {
        int off, HW;
        const float* src;
        if (idx < 1572864)      { off = 0;       HW = 12288; src = f0; }
        else if (idx < 1966080) { off = 1572864; HW = 3072;  src = f1; }
        else if (idx < 2064384) { off = 1966080; HW = 768;   src = f2; }
        else                    { off = 2064384; HW = 192;   src = f3; }
        int r = idx - off;
        int c = r / HW, p = r - c * HW;          // src layout [128][HW]
        fmapT[off + p * 128 + c] = f2b(src[r]);  // dst layout [HW][128]
    } else if (idx < FT + 933888) {
        int j = idx - FT;
        int n = j / KPAD, k = j - n * KPAD;
        W1T[j] = (k < K_RAW) ? f2b(w1[k * 384 + n]) : (unsigned short)0;
    } else if (idx < FT + 933888 + 98304) {
        int j = idx - (FT + 933888);
        int n = j / 384, k = j - n * 384;
        W2T[j] = f2b(w2[k * 256 + n]);
    }
}

// ---------------------------------------------------------------------------
// k_corr: one block (256 thr, 4 waves) per point. grid = CHUNK.
//   fA[64][136] bf16: bilinear support feats (row hw = a*7+b, a = x-off idx)
//   fB[64][136] bf16: template feats (row ij)
//   S = fA . fB^T via 16x16x32 bf16 MFMA; X row (2432, zero-padded K).
// ---------------------------------------------------------------------------
__global__ __launch_bounds__(256) void k_corr(
    const unsigned short* __restrict__ fm,   // level's [H*W,128] bf16 fmapT
    const float* __restrict__ tf,            // level's tfeat fp32 [49,4096,128]
    const float* __restrict__ coords,        // fp32 [4096,2]
    unsigned short* __restrict__ X,          // [CHUNK, 2432] bf16
    int W, int H, float scale, int n0)
{
    __shared__ unsigned short fA[64 * 136];
    __shared__ unsigned short fB[64 * 136];
    const int tid = threadIdx.x;
    const int nl = blockIdx.x;        // local row in chunk
    const int n  = n0 + nl;           // global point id

    const float px = coords[2 * n]     * scale;
    const float py = coords[2 * n + 1] * scale;

    // zero pad rows 49..63 of both LDS arrays (15*136 = 2040 each)
    for (int i = tid; i < 2040; i += 256) {
        fA[49 * 136 + i] = 0;
        fB[49 * 136 + i] = 0;
    }
    // stage template (fp32 -> bf16): 49 rows x 16 chunks of 8 ch
    for (int i = tid; i < 784; i += 256) {
        int g = i >> 4, c8 = i & 15;
        const float* p = tf + (size_t)g * (NPTS * 128) + (size_t)n * 128 + c8 * 8;
        float v[8];
#pragma unroll
        for (int j = 0; j < 8; ++j) v[j] = p[j];
        *reinterpret_cast<uint4*>(&fB[g * 136 + c8 * 8]) = pack8(v);
    }
    // bilinear gather into fA: sample s=(a,b): x-offset a-3, y-offset b-3
    for (int i = tid; i < 784; i += 256) {
        int s = i >> 4, c8 = i & 15;
        int a = s / 7, b = s - a * 7;
        float sx = px + (float)(a - 3);
        float sy = py + (float)(b - 3);
        float x0f = floorf(sx), y0f = floorf(sy);
        float wx = sx - x0f, wy = sy - y0f;
        int x0 = (int)x0f, y0 = (int)y0f;
        float acc[8] = {0.f, 0.f, 0.f, 0.f, 0.f, 0.f, 0.f, 0.f};
#pragma unroll
        for (int dy = 0; dy < 2; ++dy) {
            int yi = y0 + dy;
            if (yi < 0 || yi >= H) continue;
            float wyv = dy ? wy : 1.0f - wy;
#pragma unroll
            for (int dx = 0; dx < 2; ++dx) {
                int xi = x0 + dx;
                if (xi < 0 || xi >= W) continue;
                float wv = wyv * (dx ? wx : 1.0f - wx);
                uint4 v = *reinterpret_cast<const uint4*>(
                    fm + (size_t)(yi * W + xi) * 128 + c8 * 8);
                float f[8]; unpack8(v, f);
#pragma unroll
                for (int j = 0; j < 8; ++j) acc[j] += wv * f[j];
            }
        }
        *reinterpret_cast<uint4*>(&fA[s * 136 + c8 * 8]) = pack8(acc);
    }
    unsigned short* Xrow = X + (size_t)nl * KPAD;
    if (tid < 31) Xrow[K_RAW + tid] = 0;   // zero K padding
    __syncthreads();

    // MFMA: wave w -> S rows [16w,16w+16); 4 col tiles; K=128 in 4 steps
    const int wave = tid >> 6, lane = tid & 63;
    const int la = lane & 15, lq = lane >> 4;
    const int m0 = wave * 16;
    bf16x8 af[4];
#pragma unroll
    for (int kt = 0; kt < 4; ++kt)
        af[kt] = *reinterpret_cast<const bf16x8*>(&fA[(m0 + la) * 136 + kt * 32 + lq * 8]);
#pragma unroll
    for (int nt = 0; nt < 4; ++nt) {
        f32x4 acc = {0.f, 0.f, 0.f, 0.f};
#pragma unroll
        for (int kt = 0; kt < 4; ++kt) {
            bf16x8 bfr = *reinterpret_cast<const bf16x8*>(&fB[(nt * 16 + la) * 136 + kt * 32 + lq * 8]);
            acc = __builtin_amdgcn_mfma_f32_16x16x32_bf16(af[kt], bfr, acc, 0, 0, 0);
        }
#pragma unroll
        for (int r = 0; r < 4; ++r) {
            int m = m0 + lq * 4 + r;     // hw
            int nn = nt * 16 + la;       // ij
            if (m < 49 && nn < 49) Xrow[m * 49 + nn] = f2b(acc[r]);
        }
    }
}

// ---------------------------------------------------------------------------
// k_gemm1: H = gelu(X @ W1 + b1). M=CHUNK(1024), N=384, K=2432.
// BM=64, BN=128, BK=32. grid 16*3=48. 4 waves 2x2, wave tile 32x64.
// ---------------------------------------------------------------------------
__global__ __launch_bounds__(256) void k_gemm1(
    const unsigned short* __restrict__ X,    // [1024, 2432] bf16
    const unsigned short* __restrict__ W1T,  // [384, 2432] bf16
    const float* __restrict__ b1,            // [384] fp32
    unsigned short* __restrict__ Hout)       // [1024, 384] bf16
{
    __shared__ unsigned short Al[64 * 40];
    __shared__ unsigned short Bl[128 * 40];
    const int tid = threadIdx.x;
    const int bx = blockIdx.x;
    const int bm = bx / 3, bn = bx - bm * 3;
    const int m_base = bm * 64, n_base = bn * 128;

    const int wave = tid >> 6, lane = tid & 63;
    const int wm = wave >> 1, wn = wave & 1;
    const int la = lane & 15, lq = lane >> 4;

    f32x4 acc[2][4];
#pragma unroll
    for (int i = 0; i < 2; ++i)
#pragma unroll
        for (int j = 0; j < 4; ++j) acc[i][j] = {0.f, 0.f, 0.f, 0.f};

    const int a_row = tid >> 2, a_c8 = (tid & 3) * 8;
    for (int k0 = 0; k0 < KPAD; k0 += 32) {
        {   // stage A: 64 rows x 32 k
            uint4 v = *reinterpret_cast<const uint4*>(
                X + (size_t)(m_base + a_row) * KPAD + k0 + a_c8);
            *reinterpret_cast<uint4*>(&Al[a_row * 40 + a_c8]) = v;
        }
#pragma unroll
        for (int i = 0; i < 2; ++i) {  // stage B: 128 rows x 32 k
            int idx = tid + i * 256;
            int row = idx >> 2, c8 = (idx & 3) * 8;
            uint4 v = *reinterpret_cast<const uint4*>(
                W1T + (size_t)(n_base + row) * KPAD + k0 + c8);
            *reinterpret_cast<uint4*>(&Bl[row * 40 + c8]) = v;
        }
        __syncthreads();
        bf16x8 af[2], bfr[4];
#pragma unroll
        for (int mt = 0; mt < 2; ++mt)
            af[mt] = *reinterpret_cast<const bf16x8*>(&Al[(wm * 32 + mt * 16 + la) * 40 + lq * 8]);
#pragma unroll
        for (int nt = 0; nt < 4; ++nt)
            bfr[nt] = *reinterpret_cast<const bf16x8*>(&Bl[(wn * 64 + nt * 16 + la) * 40 + lq * 8]);
#pragma unroll
        for (int mt = 0; mt < 2; ++mt)
#pragma unroll
            for (int nt = 0; nt < 4; ++nt)
                acc[mt][nt] = __builtin_amdgcn_mfma_f32_16x16x32_bf16(af[mt], bfr[nt], acc[mt][nt], 0, 0, 0);
        __syncthreads();
    }
#pragma unroll
    for (int mt = 0; mt < 2; ++mt) {
#pragma unroll
        for (int nt = 0; nt < 4; ++nt) {
            int nn = n_base + wn * 64 + nt * 16 + la;
            float bias = b1[nn];
#pragma unroll
            for (int r = 0; r < 4; ++r) {
                int m = m_base + wm * 32 + mt * 16 + lq * 4 + r;
                float v = acc[mt][nt][r] + bias;
                v = 0.5f * v * (1.0f + erff(v * 0.70710678118654752f));  // exact GELU
                Hout[(size_t)m * 384 + nn] = f2b(v);
            }
        }
    }
}

// ---------------------------------------------------------------------------
// k_gemm2: out[n0+m, lvl*256 + nn] = H @ W2 + b2 (fp32 out).
// M=1024, N=256, K=384. BM=64, BN=128. grid 16*2=32.
// ---------------------------------------------------------------------------
__global__ __launch_bounds__(256) void k_gemm2(
    const unsigned short* __restrict__ Hin,  // [1024, 384] bf16
    const unsigned short* __restrict__ W2T,  // [256, 384] bf16
    const float* __restrict__ b2,            // [256] fp32
    float* __restrict__ out,                 // [4096, 1024] fp32
    int lvl, int n0)
{
    __shared__ unsigned short Al[64 * 40];
    __shared__ unsigned short Bl[128 * 40];
    const int tid = threadIdx.x;
    const int bx = blockIdx.x;
    const int bm = bx >> 1, bn = bx & 1;
    const int m_base = bm * 64, n_base = bn * 128;

    const int wave = tid >> 6, lane = tid & 63;
    const int wm = wave >> 1, wn = wave & 1;
    const int la = lane & 15, lq = lane >> 4;

    f32x4 acc[2][4];
#pragma unroll
    for (int i = 0; i < 2; ++i)
#pragma unroll
        for (int j = 0; j < 4; ++j) acc[i][j] = {0.f, 0.f, 0.f, 0.f};

    const int a_row = tid >> 2, a_c8 = (tid & 3) * 8;
    for (int k0 = 0; k0 < 384; k0 += 32) {
        {
            uint4 v = *reinterpret_cast<const uint4*>(
                Hin + (size_t)(m_base + a_row) * 384 + k0 + a_c8);
            *reinterpret_cast<uint4*>(&Al[a_row * 40 + a_c8]) = v;
        }
#pragma unroll
        for (int i = 0; i < 2; ++i) {
            int idx = tid + i * 256;
            int row = idx >> 2, c8 = (idx & 3) * 8;
            uint4 v = *reinterpret_cast<const uint4*>(
                W2T + (size_t)(n_base + row) * 384 + k0 + c8);
            *reinterpret_cast<uint4*>(&Bl[row * 40 + c8]) = v;
        }
        __syncthreads();
        bf16x8 af[2], bfr[4];
#pragma unroll
        for (int mt = 0; mt < 2; ++mt)
            af[mt] = *reinterpret_cast<const bf16x8*>(&Al[(wm * 32 + mt * 16 + la) * 40 + lq * 8]);
#pragma unroll
        for (int nt = 0; nt < 4; ++nt)
            bfr[nt] = *reinterpret_cast<const bf16x8*>(&Bl[(wn * 64 + nt * 16 + la) * 40 + lq * 8]);
#pragma unroll
        for (int mt = 0; mt < 2; ++mt)
#pragma unroll
            for (int nt = 0; nt < 4; ++nt)
                acc[mt][nt] = __builtin_amdgcn_mfma_f32_16x16x32_bf16(af[mt], bfr[nt], acc[mt][nt], 0, 0, 0);
        __syncthreads();
    }
#pragma unroll
    for (int mt = 0; mt < 2; ++mt) {
#pragma unroll
        for (int nt = 0; nt < 4; ++nt) {
            int nn = n_base + wn * 64 + nt * 16 + la;
            float bias = b2[nn];
#pragma unroll
            for (int r = 0; r < 4; ++r) {
                int m = m_base + wm * 32 + mt * 16 + lq * 4 + r;
                out[(size_t)(n0 + m) * 1024 + lvl * 256 + nn] = acc[mt][nt][r] + bias;
            }
        }
    }
}

// ---------------------------------------------------------------------------
extern "C" void kernel_launch(void* const* d_in, const int* in_sizes, int n_in,
                              void* d_out, int out_size, void* d_ws, size_t ws_size,
                              hipStream_t stream)
{
    const float *fm[4], *tf[4], *coords, *w1, *b1, *w2, *b2;
    if (n_in >= 13 && in_sizes[0] == 384) {
        // alphabetical: b1,b2,coords,fmaps0-3,tfeat0-3,w1,w2
        b1 = (const float*)d_in[0]; b2 = (const float*)d_in[1];
        coords = (const float*)d_in[2];
        for (int i = 0; i < 4; ++i) fm[i] = (const float*)d_in[3 + i];
        for (int i = 0; i < 4; ++i) tf[i] = (const float*)d_in[7 + i];
        w1 = (const float*)d_in[11]; w2 = (const float*)d_in[12];
    } else if (n_in >= 13 && in_sizes[1] == 25690112) {
        // setup_inputs dict order: fmaps0,tfeat0,fmaps1,tfeat1,...,coords,w1,b1,w2,b2
        for (int i = 0; i < 4; ++i) { fm[i] = (const float*)d_in[2 * i];
                                      tf[i] = (const float*)d_in[2 * i + 1]; }
        coords = (const float*)d_in[8];
        w1 = (const float*)d_in[9];  b1 = (const float*)d_in[10];
        w2 = (const float*)d_in[11]; b2 = (const float*)d_in[12];
    } else {
        // reference-arg order: fmaps0-3, coords, tfeat0-3, w1, b1, w2, b2
        for (int i = 0; i < 4; ++i) fm[i] = (const float*)d_in[i];
        coords = (const float*)d_in[4];
        for (int i = 0; i < 4; ++i) tf[i] = (const float*)d_in[5 + i];
        w1 = (const float*)d_in[9];  b1 = (const float*)d_in[10];
        w2 = (const float*)d_in[11]; b2 = (const float*)d_in[12];
    }

    char* ws = (char*)d_ws;
    unsigned short* X     = (unsigned short*)(ws);              // 1024*2432*2 = 4,980,736
    unsigned short* Hbuf  = (unsigned short*)(ws + 4980736);    // 1024*384*2  =   786,432
    unsigned short* fmapT = (unsigned short*)(ws + 5767168);    // 2,088,960*2 = 4,177,920
    unsigned short* W1T   = (unsigned short*)(ws + 9945088);    // 933,888*2   = 1,867,776
    unsigned short* W2T   = (unsigned short*)(ws + 11812864);   // 98,304*2    =   196,608
    // total ws use: 12,009,472 bytes

    hipLaunchKernelGGL(k_prep, dim3(12192), dim3(256), 0, stream,
                       fm[0], fm[1], fm[2], fm[3], w1, w2, fmapT, W1T, W2T);

    const int   cW[4]   = {128, 64, 32, 16};
    const int   cH[4]   = {96, 48, 24, 12};
    const int   cOff[4] = {0, 1572864, 1966080, 2064384};
    const float cS[4]   = {1.0f, 0.5f, 0.25f, 0.125f};

    for (int l = 0; l < 4; ++l) {
        for (int c = 0; c < 4; ++c) {
            int n0 = c * CHUNK;
            hipLaunchKernelGGL(k_corr, dim3(CHUNK), dim3(256), 0, stream,
                               fmapT + cOff[l], tf[l], coords, X,
                               cW[l], cH[l], cS[l], n0);
            hipLaunchKernelGGL(k_gemm1, dim3(48), dim3(256), 0, stream,
                               X, W1T, b1, Hbuf);
            hipLaunchKernelGGL(k_gemm2, dim3(32), dim3(256), 0, stream,
                               Hbuf, W2T, b2, (float*)d_out, l, n0);
        }
    }
}